// Round 16
// baseline (176.053 us; speedup 1.0000x reference)
//
#include <hip/hip_runtime.h>
#include <hip/hip_bf16.h>
#include <math.h>

typedef __attribute__((ext_vector_type(8))) short bf16x8;
typedef __attribute__((ext_vector_type(4))) short bf16x4;
typedef __attribute__((ext_vector_type(4))) float f32x4;

#define MFMA32 __builtin_amdgcn_mfma_f32_16x16x32_bf16
#define MFMA16 __builtin_amdgcn_mfma_f32_16x16x16bf16_1k

#define QSCALE 0.25503485964546277f  // (1/sqrt(32)) * log2(e)

__device__ inline short bfbits(float f) {
  union { float f; unsigned u; } v; v.f = f;
  unsigned r = v.u + 0x7fffu + ((v.u >> 16) & 1u);
  return (short)(r >> 16);
}
__device__ inline float bf2f(unsigned short u) {
  union { unsigned u; float f; } v; v.u = ((unsigned)u) << 16; return v.f;
}
__device__ inline void gll16(const void* g, void* l) {
  __builtin_amdgcn_global_load_lds(
      (const __attribute__((address_space(1))) unsigned*)g,
      (__attribute__((address_space(3))) unsigned*)l, 16, 0, 0);
}
// pack 4 f32 -> bf16x4 via v_cvt_pk_bf16_f32 (RTNE)
__device__ inline bf16x4 pk4(float e0, float e1, float e2, float e3) {
  unsigned lo, hi;
  asm("v_cvt_pk_bf16_f32 %0, %1, %2" : "=v"(lo) : "v"(e0), "v"(e1));
  asm("v_cvt_pk_bf16_f32 %0, %1, %2" : "=v"(hi) : "v"(e2), "v"(e3));
  union { unsigned u[2]; bf16x4 v; } cv;
  cv.u[0] = lo; cv.u[1] = hi;
  return cv.v;
}

// ---------------------------------------------------------------------------
// prep2: ONE launch, three jobs, exact block ranges.
//   bid [0,512)      : bias_bf[h][row] = bf16(sum_z pair[row,z]*bproj[z,h])
//   bid [512,1792)   : Wh[h][c][k] (q|k|v|gate per head, q prescaled) 1024 blk
//                      + Woutt[col][k] 256 blk (exact)
//   bid [1792,5888)  : X f32 -> Xbf bf16
// ---------------------------------------------------------------------------
__global__ __launch_bounds__(256) void prep2_kernel(
    const float* __restrict__ X, const float* __restrict__ pair,
    const float* __restrict__ bproj, const float* __restrict__ Wg,
    const float* __restrict__ Wqkv, const float* __restrict__ Wout,
    short* __restrict__ Xbf, short* __restrict__ bias_bf,
    short* __restrict__ Wh, short* __restrict__ Woutt) {
  __shared__ float bp[1024];      // bp[h*128+z] = bproj[z*8+h]
  __shared__ float red[128][8];
  int bid = blockIdx.x;
  int t = threadIdx.x;
  if (bid < 512) {  // ---- bias ----
    for (int i = t; i < 1024; i += 256)
      bp[i] = bproj[(i & 127) * 8 + (i >> 7)];
    __syncthreads();
    int row = bid * 128 + (t & 127);
    int zh = t >> 7;  // wave-uniform z-half
    const float4* src = (const float4*)(pair + (size_t)row * 128 + zh * 64);
    float acc[8] = {};
#pragma unroll
    for (int z4 = 0; z4 < 16; ++z4) {
      float4 v = src[z4];
#pragma unroll
      for (int h = 0; h < 8; ++h) {
        float4 b = *(const float4*)&bp[h * 128 + zh * 64 + z4 * 4];  // bcast
        acc[h] += v.x * b.x + v.y * b.y + v.z * b.z + v.w * b.w;
      }
    }
    if (t >= 128) {
#pragma unroll
      for (int h = 0; h < 8; ++h) red[t - 128][h] = acc[h];
    }
    __syncthreads();
    if (t < 128) {
#pragma unroll
      for (int h = 0; h < 8; ++h)
        bias_bf[(size_t)h * 65536 + row] = bfbits(acc[h] + red[t][h]);
    }
  } else if (bid < 1792) {  // ---- Wh + Woutt (exact 1280 blocks) ----
    int idx = (bid - 512) * 256 + t;  // [0, 327680)
    if (idx < 262144) {
      // Wh[h][c][k]: c<32 q (x QSCALE) | 32-63 k | 64-95 v | 96-127 gate
      int h = idx >> 15, rem = idx & 32767;
      int c = rem >> 8, k = rem & 255;
      float v;
      if (c < 96) {
        v = Wqkv[k * 768 + h * 96 + c];
        if (c < 32) v *= QSCALE;
      } else {
        v = Wg[k * 256 + h * 32 + (c - 96)];
      }
      Wh[idx] = bfbits(v);
    } else {
      int j = idx - 262144;  // [0, 65536) exact
      int col = j >> 8, k = j & 255;
      Woutt[j] = bfbits(Wout[k * 256 + col]);
    }
  } else {  // ---- xconv (4096 blocks) ----
    size_t i = ((size_t)(bid - 1792) * 256 + t) * 8;
    float4 a = *(const float4*)(X + i);
    float4 b = *(const float4*)(X + i + 4);
    bf16x8 o = {bfbits(a.x), bfbits(a.y), bfbits(a.z), bfbits(a.w),
                bfbits(b.x), bfbits(b.y), bfbits(b.z), bfbits(b.w)};
    *(bf16x8*)(Xbf + i) = o;
  }
}

// ---------------------------------------------------------------------------
// fused_qkvattn v2: per (s,h) block (1024 blocks, 512 thr = 8 waves).
// Phase 1: GEMM Xbf[256x256] @ Wh[h]^T. wn==0 waves (q|k cols) use SWAPPED
//          operands (W as A, X as B) so fragments land transposed -> packed
//          bf16x4 LDS scatter. wn==1 (v|gate) unswapped (already packed).
// Phase 2: scatter: K,Q slot-swizzled [256][32]; V,gate [c][p].
// Phase 3: per-wave qtr-staggered attn: simT=K@Q^T, E=exp2, U=E@V, L=E@1,
//          BV=bias@V; out=(U*rcp(L)+BV)*gate.
// Output head-major attn[h][grow][32] -> contiguous 16KB stripe per block.
// ---------------------------------------------------------------------------
__global__ __launch_bounds__(512, 4) void fused_qkvattn(
    const short* __restrict__ Xbf, const short* __restrict__ Wh,
    const short* __restrict__ bias_bf, short* __restrict__ attn_bf) {
  // LDS (shorts): GEMM: A dbuf [0,16384), B dbuf [16384,24576).
  // Post-GEMM: Ks [0,8192) | Qs [8192,16384) | Vt [16384,24704) [32][260]
  //            Gs [24704,33024) [32][260].  Res reuses Ks.
  __shared__ short lds[33024];
  int t = threadIdx.x;
  int lane = t & 63, wid = t >> 6;
  int lq = lane & 15, lg = lane >> 4;
  int flat = blockIdx.x;
  int xcd = flat & 7, local = flat >> 3;
  int h = local & 7;
  int s = xcd * 16 + (local >> 3);  // same-s blocks consecutive on one XCD

  const short* xrow0 = Xbf + (size_t)s * 65536;  // 256 rows x 256 k
  const short* whh = Wh + h * 32768;             // 128 cols x 256 k

  // ================= Phase 1: GEMM =================
  int wm = wid >> 1, wn = wid & 1;  // 4 m-tiles x 2 n-tiles of 64
  auto stageA = [&](int kq, int buf) {
#pragma unroll
    for (int c = 0; c < 2; ++c) {
      int D = c * 8192 + t * 16;  // byte offset in A-buf (16KB)
      int row = D >> 6;
      int sl = ((D >> 4) & 3) ^ ((row >> 1) & 3);
      gll16(xrow0 + (size_t)row * 256 + kq * 32 + sl * 8,
            (char*)lds + buf * 16384 + D);
    }
  };
  auto stageB = [&](int kq, int buf) {
    int D = t * 16;  // byte offset in B-buf (8KB)
    int col = D >> 6;
    int sl = ((D >> 4) & 3) ^ ((col >> 1) & 3);
    gll16(whh + (size_t)col * 256 + kq * 32 + sl * 8,
          (char*)lds + 32768 + buf * 8192 + D);
  };

  f32x4 acc[4][4];
#pragma unroll
  for (int a = 0; a < 4; ++a)
#pragma unroll
    for (int b = 0; b < 4; ++b) acc[a][b] = {0.f, 0.f, 0.f, 0.f};

  stageA(0, 0);
  stageB(0, 0);
  __syncthreads();

  for (int kq = 0; kq < 8; ++kq) {
    int buf = kq & 1;
    if (kq < 7) {
      stageA(kq + 1, buf ^ 1);
      stageB(kq + 1, buf ^ 1);
    }
    bf16x8 afr[4], bfr[4];
#pragma unroll
    for (int mf = 0; mf < 4; ++mf) {
      int row = wm * 64 + mf * 16 + lq;
      int sl = lg ^ ((row >> 1) & 3);
      afr[mf] = *(const bf16x8*)((const char*)lds + buf * 16384 + row * 64 +
                                 sl * 16);
    }
#pragma unroll
    for (int nf = 0; nf < 4; ++nf) {
      int col = wn * 64 + nf * 16 + lq;
      int sl = lg ^ ((col >> 1) & 3);
      bfr[nf] = *(const bf16x8*)((const char*)lds + 32768 + buf * 8192 +
                                 col * 64 + sl * 16);
    }
    if (wn == 0) {  // swapped: D[row=c][col=p] -> packed scatter later
#pragma unroll
      for (int mf = 0; mf < 4; ++mf)
#pragma unroll
        for (int nf = 0; nf < 4; ++nf)
          acc[mf][nf] = MFMA32(bfr[nf], afr[mf], acc[mf][nf], 0, 0, 0);
    } else {
#pragma unroll
      for (int mf = 0; mf < 4; ++mf)
#pragma unroll
        for (int nf = 0; nf < 4; ++nf)
          acc[mf][nf] = MFMA32(afr[mf], bfr[nf], acc[mf][nf], 0, 0, 0);
    }
    __syncthreads();
  }

  // ================= Phase 2: scatter to LDS =================
  short* Vt = lds + 16384;   // [32][260] V^T
  short* Gs = lds + 24704;   // [32][260] gate^T (sigmoid applied)
  if (wn == 0) {  // q|k, swapped frags: p = wm*64+mf*16+lq, c = nf*16+lg*4+j
#pragma unroll
    for (int mf = 0; mf < 4; ++mf)
#pragma unroll
      for (int nf = 0; nf < 4; ++nf) {
        int p = wm * 64 + mf * 16 + lq;
        int c0 = nf * 16 + lg * 4;           // j contiguous in c
        int cc0 = c0 & 31;
        char* base = (char*)lds + ((nf < 2) ? 16384 : 0);  // q->Qs, k->Ks
        int slot = (cc0 >> 3) ^ ((p >> 1) & 3);
        bf16x4 pk = {bfbits(acc[mf][nf][0]), bfbits(acc[mf][nf][1]),
                     bfbits(acc[mf][nf][2]), bfbits(acc[mf][nf][3])};
        *(bf16x4*)(base + p * 64 + slot * 16 + ((cc0 & 7) * 2)) = pk;
      }
  } else {  // v|gate -> [c][p] packed bf16x4 writes (j contiguous in p)
#pragma unroll
    for (int mf = 0; mf < 4; ++mf)
#pragma unroll
      for (int nf = 0; nf < 4; ++nf) {
        int R0 = wm * 64 + mf * 16 + lg * 4;
        if (nf < 2) {
          int c = nf * 16 + lq;
          bf16x4 v4 = {bfbits(acc[mf][nf][0]), bfbits(acc[mf][nf][1]),
                       bfbits(acc[mf][nf][2]), bfbits(acc[mf][nf][3])};
          *(bf16x4*)&Vt[c * 260 + R0] = v4;
        } else {
          int c = (nf - 2) * 16 + lq;
          bf16x4 g4;
#pragma unroll
          for (int j = 0; j < 4; ++j)
            g4[j] = bfbits(
                __builtin_amdgcn_rcpf(1.f + __expf(-acc[mf][nf][j])));
          *(bf16x4*)&Gs[c * 260 + R0] = g4;
        }
      }
  }
  __syncthreads();

  // ================= Phase 3: attention (qtr-staggered) =================
  int rbase = wid * 32;  // 8 waves x 32 rows = 256 rows
  int qrow0 = rbase + lq, qrow1 = rbase + 16 + lq;
  bf16x8 qf0 = *(const bf16x8*)((const char*)lds + 16384 + qrow0 * 64 +
                                ((lg ^ ((qrow0 >> 1) & 3)) << 4));
  bf16x8 qf1 = *(const bf16x8*)((const char*)lds + 16384 + qrow1 * 64 +
                                ((lg ^ ((qrow1 >> 1) & 3)) << 4));
  const short* bb0 =
      bias_bf + ((size_t)h * 256 + rbase + lq) * 256 + lg * 8;  // 16B frags
  const short* bb1 = bb0 + 16 * 256;

  f32x4 U[2][2], BV[2][2], L[2];
#pragma unroll
  for (int ri = 0; ri < 2; ++ri) {
    L[ri] = {0.f, 0.f, 0.f, 0.f};
#pragma unroll
    for (int ct = 0; ct < 2; ++ct) {
      U[ri][ct] = {0.f, 0.f, 0.f, 0.f};
      BV[ri][ct] = {0.f, 0.f, 0.f, 0.f};
    }
  }
  const bf16x4 ones = {16256, 16256, 16256, 16256};  // bf16 1.0

#pragma unroll
  for (int qq = 0; qq < 4; ++qq) {
    int qtr = (qq + (wid & 3)) & 3;  // stagger waves across sub-phases
    f32x4 sim[2][4];
#pragma unroll
    for (int ri = 0; ri < 2; ++ri)
#pragma unroll
      for (int i = 0; i < 4; ++i) sim[ri][i] = {0.f, 0.f, 0.f, 0.f};
    __builtin_amdgcn_s_setprio(1);
#pragma unroll
    for (int i = 0; i < 4; ++i) {
      int row = (qtr * 4 + i) * 16 + lq;
      bf16x8 kf = *(const bf16x8*)((const char*)lds + row * 64 +
                                   ((lg ^ ((row >> 1) & 3)) << 4));
      sim[0][i] = MFMA32(kf, qf0, sim[0][i], 0, 0, 0);
      sim[1][i] = MFMA32(kf, qf1, sim[1][i], 0, 0, 0);
    }
#pragma unroll
    for (int c2 = 0; c2 < 2; ++c2) {
      int chunk = qtr * 2 + c2;
      bf16x8 b0 = *(const bf16x8*)(bb0 + chunk * 32);
      bf16x8 b1 = *(const bf16x8*)(bb1 + chunk * 32);
      bf16x8 v0 = *(const bf16x8*)&Vt[lq * 260 + chunk * 32 + lg * 8];
      bf16x8 v1 = *(const bf16x8*)&Vt[(16 + lq) * 260 + chunk * 32 + lg * 8];
      BV[0][0] = MFMA32(b0, v0, BV[0][0], 0, 0, 0);
      BV[0][1] = MFMA32(b0, v1, BV[0][1], 0, 0, 0);
      BV[1][0] = MFMA32(b1, v0, BV[1][0], 0, 0, 0);
      BV[1][1] = MFMA32(b1, v1, BV[1][1], 0, 0, 0);
    }
    __builtin_amdgcn_s_setprio(0);

    bf16x4 af[2][4];
#pragma unroll
    for (int ri = 0; ri < 2; ++ri)
#pragma unroll
      for (int i = 0; i < 4; ++i)
        af[ri][i] = pk4(__builtin_amdgcn_exp2f(sim[ri][i][0]),
                        __builtin_amdgcn_exp2f(sim[ri][i][1]),
                        __builtin_amdgcn_exp2f(sim[ri][i][2]),
                        __builtin_amdgcn_exp2f(sim[ri][i][3]));

    __builtin_amdgcn_s_setprio(1);
#pragma unroll
    for (int i = 0; i < 4; ++i) {
      int kc = qtr * 4 + i;
      bf16x4 vf0 = *(const bf16x4*)&Vt[lq * 260 + kc * 16 + lg * 4];
      bf16x4 vf1 = *(const bf16x4*)&Vt[(16 + lq) * 260 + kc * 16 + lg * 4];
#pragma unroll
      for (int ri = 0; ri < 2; ++ri) {
        U[ri][0] = MFMA16(af[ri][i], vf0, U[ri][0], 0, 0, 0);
        U[ri][1] = MFMA16(af[ri][i], vf1, U[ri][1], 0, 0, 0);
        L[ri]    = MFMA16(af[ri][i], ones, L[ri], 0, 0, 0);
      }
    }
    __builtin_amdgcn_s_setprio(0);
  }

  __syncthreads();  // done reading Ks/Qs; reuse Ks as Res [256][32]
  short* Res = lds;

#pragma unroll
  for (int ri = 0; ri < 2; ++ri) {
    f32x4 inv;
#pragma unroll
    for (int j = 0; j < 4; ++j) inv[j] = __builtin_amdgcn_rcpf(L[ri][j]);
#pragma unroll
    for (int ct = 0; ct < 2; ++ct) {
      int c = ct * 16 + lq;
      bf16x4 g4 = *(const bf16x4*)&Gs[c * 260 + rbase + ri * 16 + lg * 4];
#pragma unroll
      for (int j = 0; j < 4; ++j) {
        int rl = rbase + ri * 16 + lg * 4 + j;
        Res[rl * 32 + c] =
            bfbits((U[ri][ct][j] * inv[j] + BV[ri][ct][j]) *
                   bf2f((unsigned short)g4[j]));
      }
    }
  }
  __syncthreads();

  // head-major coalesced store: attn[h][s*256+row][32] — contiguous 16KB
  {
    int row = t >> 1, hf = t & 1;
    size_t o = (size_t)h * 1048576 + ((size_t)(s * 256 + row)) * 32 + hf * 16;
    bf16x8 r0 = *(const bf16x8*)&Res[row * 32 + hf * 16];
    bf16x8 r1 = *(const bf16x8*)&Res[row * 32 + hf * 16 + 8];
    *(bf16x8*)&attn_bf[o] = r0;
    *(bf16x8*)&attn_bf[o + 8] = r1;
  }
}

// ---------------------------------------------------------------------------
// gemm_out: attn[h][grow][32] (head-major) @ Woutt^T -> out f32.
// A-stage maps original k = h*32+c to the head-major layout per 16B chunk.
// ---------------------------------------------------------------------------
__global__ __launch_bounds__(256) void gemm_out2(
    const short* __restrict__ A, const short* __restrict__ Wt,
    float* __restrict__ out) {
  __shared__ short As2[2][128 * 64];
  __shared__ short Bs2[2][128 * 64];
  int t = threadIdx.x;
  int lane = t & 63, wid = t >> 6;
  int lq = lane & 15, lg = lane >> 4;
  int wm = wid >> 1, wn = wid & 1;
  int r0 = blockIdx.x * 128, n0 = blockIdx.y * 128;

  auto stage = [&](int s, int buf) {
#pragma unroll
    for (int q = 0; q < 4; ++q) {
      int P = wid * 4096 + q * 1024 + lane * 16;
      int row = P >> 7, kb = P & 127;
      int klog = kb ^ ((row & 7) << 4);
      int kel = s * 64 + (klog >> 1);  // original k index, 8-elem chunk
      gll16(A + ((size_t)(kel >> 5) * 1048576 +
                 (size_t)(r0 + row) * 32 + (kel & 31)),
            (char*)&As2[buf][0] + wid * 4096 + q * 1024);
      gll16((const char*)Wt + ((size_t)(n0 + row) * 512 + s * 128 + klog),
            (char*)&Bs2[buf][0] + wid * 4096 + q * 1024);
    }
  };

  f32x4 acc[4][4];
#pragma unroll
  for (int a = 0; a < 4; ++a)
#pragma unroll
    for (int b = 0; b < 4; ++b) acc[a][b] = {0.f, 0.f, 0.f, 0.f};

  stage(0, 0);
  __syncthreads();
  for (int s = 0; s < 4; ++s) {
    if (s < 3) stage(s + 1, (s + 1) & 1);
    bf16x8 afr[4][2], bfr[4][2];
#pragma unroll
    for (int kcl = 0; kcl < 2; ++kcl) {
#pragma unroll
      for (int mf = 0; mf < 4; ++mf) {
        int row = wm * 64 + mf * 16 + lq;
        int kb = (((kcl << 6) | (lg << 4))) ^ ((row & 7) << 4);
        afr[mf][kcl] = *(const bf16x8*)((const char*)&As2[s & 1][0] + row * 128 + kb);
      }
#pragma unroll
      for (int nf = 0; nf < 4; ++nf) {
        int col = wn * 64 + nf * 16 + lq;
        int kb = (((kcl << 6) | (lg << 4))) ^ ((col & 7) << 4);
        bfr[nf][kcl] = *(const bf16x8*)((const char*)&Bs2[s & 1][0] + col * 128 + kb);
      }
    }
#pragma unroll
    for (int mf = 0; mf < 4; ++mf)
#pragma unroll
      for (int nf = 0; nf < 4; ++nf)
#pragma unroll
        for (int kcl = 0; kcl < 2; ++kcl)
          acc[mf][nf] = MFMA32(afr[mf][kcl], bfr[nf][kcl], acc[mf][nf], 0, 0, 0);
    __syncthreads();
  }
#pragma unroll
  for (int mf = 0; mf < 4; ++mf)
#pragma unroll
    for (int nf = 0; nf < 4; ++nf) {
      int col = n0 + wn * 64 + nf * 16 + lq;
#pragma unroll
      for (int j = 0; j < 4; ++j) {
        int row = r0 + wm * 64 + mf * 16 + lg * 4 + j;
        out[(size_t)row * 256 + col] = acc[mf][nf][j];
      }
    }
}

// ---------------------------------------------------------------------------
extern "C" void kernel_launch(void* const* d_in, const int* in_sizes, int n_in,
                              void* d_out, int out_size, void* d_ws,
                              size_t ws_size, hipStream_t stream) {
  const float* msa  = (const float*)d_in[0];
  const float* pair = (const float*)d_in[1];
  const float* Wg   = (const float*)d_in[2];
  const float* Wqkv = (const float*)d_in[3];
  const float* Wout = (const float*)d_in[4];
  const float* Bp   = (const float*)d_in[5];
  float* out = (float*)d_out;
  short* sw = (short*)d_ws;

  short* bias_bf = sw;                 //   524288 shorts
  short* attn_bf = sw + 524288;        //  8388608 (head-major [8][32768][32])
  short* Wh_bf   = sw + 8912896;       //   262144
  short* Woutt   = sw + 9175040;       //    65536
  short* X_bf    = sw + 9240576;       //  8388608

  hipLaunchKernelGGL(prep2_kernel, dim3(5888), dim3(256), 0, stream,
                     msa, pair, Bp, Wg, Wqkv, Wout,
                     X_bf, bias_bf, Wh_bf, Woutt);
  hipLaunchKernelGGL(fused_qkvattn, dim3(1024), dim3(512), 0, stream,
                     X_bf, Wh_bf, bias_bf, attn_bf);
  hipLaunchKernelGGL(gemm_out2, dim3(256, 2), dim3(256), 0, stream,
                     attn_bf, Woutt, out);
}

// Round 17
// 74.662 us; speedup vs baseline: 2.3580x; 2.3580x over previous
//
#include <hip/hip_runtime.h>
#include <hip/hip_bf16.h>
#include <math.h>

typedef __attribute__((ext_vector_type(8))) short bf16x8;
typedef __attribute__((ext_vector_type(4))) short bf16x4;
typedef __attribute__((ext_vector_type(4))) float f32x4;

#define MFMA32 __builtin_amdgcn_mfma_f32_16x16x32_bf16
#define MFMA16 __builtin_amdgcn_mfma_f32_16x16x16bf16_1k

#define QSCALE 0.25503485964546277f  // (1/sqrt(32)) * log2(e)

__device__ inline short bfbits(float f) {
  union { float f; unsigned u; } v; v.f = f;
  unsigned r = v.u + 0x7fffu + ((v.u >> 16) & 1u);
  return (short)(r >> 16);
}
__device__ inline float bf2f(unsigned short u) {
  union { unsigned u; float f; } v; v.u = ((unsigned)u) << 16; return v.f;
}
__device__ inline void gll16(const void* g, void* l) {
  __builtin_amdgcn_global_load_lds(
      (const __attribute__((address_space(1))) unsigned*)g,
      (__attribute__((address_space(3))) unsigned*)l, 16, 0, 0);
}
// pack 4 f32 -> bf16x4 via v_cvt_pk_bf16_f32 (RTNE)
__device__ inline bf16x4 pk4(float e0, float e1, float e2, float e3) {
  unsigned lo, hi;
  asm("v_cvt_pk_bf16_f32 %0, %1, %2" : "=v"(lo) : "v"(e0), "v"(e1));
  asm("v_cvt_pk_bf16_f32 %0, %1, %2" : "=v"(hi) : "v"(e2), "v"(e3));
  union { unsigned u[2]; bf16x4 v; } cv;
  cv.u[0] = lo; cv.u[1] = hi;
  return cv.v;
}

// ---------------------------------------------------------------------------
// prep2: ONE launch, three jobs, exact block ranges.
//   bid [0,512)      : bias_bf[h][row] = bf16(sum_z pair[row,z]*bproj[z,h])
//   bid [512,1792)   : Wh[h][c][k] (q|k|v|gate per head, q prescaled) 1024 blk
//                      + Woutt[col][k] 256 blk (exact)
//   bid [1792,5888)  : X f32 -> Xbf bf16
// ---------------------------------------------------------------------------
__global__ __launch_bounds__(256) void prep2_kernel(
    const float* __restrict__ X, const float* __restrict__ pair,
    const float* __restrict__ bproj, const float* __restrict__ Wg,
    const float* __restrict__ Wqkv, const float* __restrict__ Wout,
    short* __restrict__ Xbf, short* __restrict__ bias_bf,
    short* __restrict__ Wh, short* __restrict__ Woutt) {
  __shared__ float bp[1024];      // bp[h*128+z] = bproj[z*8+h]
  __shared__ float red[128][8];
  int bid = blockIdx.x;
  int t = threadIdx.x;
  if (bid < 512) {  // ---- bias ----
    for (int i = t; i < 1024; i += 256)
      bp[i] = bproj[(i & 127) * 8 + (i >> 7)];
    __syncthreads();
    int row = bid * 128 + (t & 127);
    int zh = t >> 7;  // wave-uniform z-half
    const float4* src = (const float4*)(pair + (size_t)row * 128 + zh * 64);
    float acc[8] = {};
#pragma unroll
    for (int z4 = 0; z4 < 16; ++z4) {
      float4 v = src[z4];
#pragma unroll
      for (int h = 0; h < 8; ++h) {
        float4 b = *(const float4*)&bp[h * 128 + zh * 64 + z4 * 4];  // bcast
        acc[h] += v.x * b.x + v.y * b.y + v.z * b.z + v.w * b.w;
      }
    }
    if (t >= 128) {
#pragma unroll
      for (int h = 0; h < 8; ++h) red[t - 128][h] = acc[h];
    }
    __syncthreads();
    if (t < 128) {
#pragma unroll
      for (int h = 0; h < 8; ++h)
        bias_bf[(size_t)h * 65536 + row] = bfbits(acc[h] + red[t][h]);
    }
  } else if (bid < 1792) {  // ---- Wh + Woutt (exact 1280 blocks) ----
    int idx = (bid - 512) * 256 + t;  // [0, 327680)
    if (idx < 262144) {
      // Wh[h][c][k]: c<32 q (x QSCALE) | 32-63 k | 64-95 v | 96-127 gate
      int h = idx >> 15, rem = idx & 32767;
      int c = rem >> 8, k = rem & 255;
      float v;
      if (c < 96) {
        v = Wqkv[k * 768 + h * 96 + c];
        if (c < 32) v *= QSCALE;
      } else {
        v = Wg[k * 256 + h * 32 + (c - 96)];
      }
      Wh[idx] = bfbits(v);
    } else {
      int j = idx - 262144;  // [0, 65536) exact
      int col = j >> 8, k = j & 255;
      Woutt[j] = bfbits(Wout[k * 256 + col]);
    }
  } else {  // ---- xconv (4096 blocks) ----
    size_t i = ((size_t)(bid - 1792) * 256 + t) * 8;
    float4 a = *(const float4*)(X + i);
    float4 b = *(const float4*)(X + i + 4);
    bf16x8 o = {bfbits(a.x), bfbits(a.y), bfbits(a.z), bfbits(a.w),
                bfbits(b.x), bfbits(b.y), bfbits(b.z), bfbits(b.w)};
    *(bf16x8*)(Xbf + i) = o;
  }
}

// ---------------------------------------------------------------------------
// fused_qkvattn v3: per (s,h) block (1024 blocks, 512 thr = 8 waves).
// Phase 1: GEMM with UNIFORM MFMA schedule; operand routing via per-wave
//          ADDRESS select (wn==0 waves get W-frag as 1st operand -> D lands
//          transposed [c][p] -> packed q/k scatter). No duplicated MFMA
//          branch (round-16 spill lesson).
// Phase 2: packed bf16x4 scatter: K,Q slot-swizzled [p][32]; V,gate [c][p].
// Phase 3: attn: simT=K@Q^T, E=exp2->pk4, U=E@V, L=E@1, BV=bias@V;
//          out=(U*rcp(L)+BV)*gate; LDS-bounce.
// Output head-major attn[h][grow][32] (full-line writes).
// ---------------------------------------------------------------------------
__global__ __launch_bounds__(512, 4) void fused_qkvattn(
    const short* __restrict__ Xbf, const short* __restrict__ Wh,
    const short* __restrict__ bias_bf, short* __restrict__ attn_bf) {
  // LDS bytes: A dbuf [0,32768), B dbuf [32768,49152).
  // Post-GEMM: Ks bytes [0,16384) | Qs [16384,32768) | Vt [32768,49408)
  //            [32][260] | Gs [49408,66048) [32][260]. Res reuses Ks.
  __shared__ short lds[33024];
  int t = threadIdx.x;
  int lane = t & 63, wid = t >> 6;
  int lq = lane & 15, lg = lane >> 4;
  int flat = blockIdx.x;
  int xcd = flat & 7, local = flat >> 3;
  int h = local & 7;
  int s = xcd * 16 + (local >> 3);  // same-s blocks on one XCD

  const short* xrow0 = Xbf + (size_t)s * 65536;  // 256 rows x 256 k
  const short* whh = Wh + h * 32768;             // 128 cols x 256 k

  // ================= Phase 1: GEMM =================
  int wm = wid >> 1, wn = wid & 1;  // 4 m-tiles x 2 n-tiles of 64
  int firstB = (wn == 0);           // wave-uniform operand routing
  auto stageA = [&](int kq, int buf) {
#pragma unroll
    for (int c = 0; c < 2; ++c) {
      int D = c * 8192 + t * 16;  // byte offset in A-buf (16KB)
      int row = D >> 6;
      int sl = ((D >> 4) & 3) ^ ((row >> 1) & 3);
      gll16(xrow0 + (size_t)row * 256 + kq * 32 + sl * 8,
            (char*)lds + buf * 16384 + D);
    }
  };
  auto stageB = [&](int kq, int buf) {
    int D = t * 16;  // byte offset in B-buf (8KB)
    int col = D >> 6;
    int sl = ((D >> 4) & 3) ^ ((col >> 1) & 3);
    gll16(whh + (size_t)col * 256 + kq * 32 + sl * 8,
          (char*)lds + 32768 + buf * 8192 + D);
  };

  f32x4 acc[4][4];
#pragma unroll
  for (int a = 0; a < 4; ++a)
#pragma unroll
    for (int b = 0; b < 4; ++b) acc[a][b] = {0.f, 0.f, 0.f, 0.f};

  stageA(0, 0);
  stageB(0, 0);
  __syncthreads();

  for (int kq = 0; kq < 8; ++kq) {
    int buf = kq & 1;
    if (kq < 7) {
      stageA(kq + 1, buf ^ 1);
      stageB(kq + 1, buf ^ 1);
    }
    bf16x8 F[4], S[4];
#pragma unroll
    for (int i = 0; i < 4; ++i) {
      int arow = wm * 64 + i * 16 + lq;
      int aoff = buf * 16384 + arow * 64 + ((lg ^ ((arow >> 1) & 3)) << 4);
      int bcol = wn * 64 + i * 16 + lq;
      int boff =
          32768 + buf * 8192 + bcol * 64 + ((lg ^ ((bcol >> 1) & 3)) << 4);
      F[i] = *(const bf16x8*)((const char*)lds + (firstB ? boff : aoff));
      S[i] = *(const bf16x8*)((const char*)lds + (firstB ? aoff : boff));
    }
#pragma unroll
    for (int a = 0; a < 4; ++a)
#pragma unroll
      for (int b = 0; b < 4; ++b)
        acc[a][b] = MFMA32(F[a], S[b], acc[a][b], 0, 0, 0);
    __syncthreads();
  }

  // ================= Phase 2: packed scatter to LDS =================
  short* Vt = lds + 16384;   // byte 32768: [32][260] V^T
  short* Gs = lds + 24704;   // byte 49408: [32][260] gate^T
  if (wn == 0) {  // q|k transposed: c = a*16+lg*4+j, p = wm*64+b*16+lq
#pragma unroll
    for (int a = 0; a < 4; ++a)
#pragma unroll
      for (int b = 0; b < 4; ++b) {
        int p = wm * 64 + b * 16 + lq;
        int c0 = a * 16 + lg * 4;
        int cc0 = c0 & 31;
        char* base = (char*)lds + ((a < 2) ? 16384 : 0);  // q->Qs, k->Ks
        int slot = (cc0 >> 3) ^ ((p >> 1) & 3);
        bf16x4 pk = {bfbits(acc[a][b][0]), bfbits(acc[a][b][1]),
                     bfbits(acc[a][b][2]), bfbits(acc[a][b][3])};
        *(bf16x4*)(base + p * 64 + slot * 16 + (cc0 & 7) * 2) = pk;
      }
  } else {  // v|gate standard: p = wm*64+a*16+lg*4+j, c = b*16+lq (+64)
#pragma unroll
    for (int a = 0; a < 4; ++a)
#pragma unroll
      for (int b = 0; b < 4; ++b) {
        int R0 = wm * 64 + a * 16 + lg * 4;
        if (b < 2) {
          int c = b * 16 + lq;
          bf16x4 v4 = {bfbits(acc[a][b][0]), bfbits(acc[a][b][1]),
                       bfbits(acc[a][b][2]), bfbits(acc[a][b][3])};
          *(bf16x4*)&Vt[c * 260 + R0] = v4;
        } else {
          int c = (b - 2) * 16 + lq;
          bf16x4 g4;
#pragma unroll
          for (int j = 0; j < 4; ++j)
            g4[j] = bfbits(
                __builtin_amdgcn_rcpf(1.f + __expf(-acc[a][b][j])));
          *(bf16x4*)&Gs[c * 260 + R0] = g4;
        }
      }
  }
  __syncthreads();

  // ================= Phase 3: attention =================
  int rbase = wid * 32;  // 8 waves x 32 rows
  int qrow0 = rbase + lq, qrow1 = rbase + 16 + lq;
  bf16x8 qf0 = *(const bf16x8*)((const char*)lds + 16384 + qrow0 * 64 +
                                ((lg ^ ((qrow0 >> 1) & 3)) << 4));
  bf16x8 qf1 = *(const bf16x8*)((const char*)lds + 16384 + qrow1 * 64 +
                                ((lg ^ ((qrow1 >> 1) & 3)) << 4));
  const short* bb0 =
      bias_bf + ((size_t)h * 256 + rbase + lq) * 256 + lg * 8;  // 16B frags
  const short* bb1 = bb0 + 16 * 256;

  f32x4 U[2][2], BV[2][2], L[2];
#pragma unroll
  for (int ri = 0; ri < 2; ++ri) {
    L[ri] = {0.f, 0.f, 0.f, 0.f};
#pragma unroll
    for (int ct = 0; ct < 2; ++ct) {
      U[ri][ct] = {0.f, 0.f, 0.f, 0.f};
      BV[ri][ct] = {0.f, 0.f, 0.f, 0.f};
    }
  }
  const bf16x4 ones = {16256, 16256, 16256, 16256};  // bf16 1.0

#pragma unroll
  for (int qtr = 0; qtr < 4; ++qtr) {
    f32x4 sim[2][4];
#pragma unroll
    for (int ri = 0; ri < 2; ++ri)
#pragma unroll
      for (int i = 0; i < 4; ++i) sim[ri][i] = {0.f, 0.f, 0.f, 0.f};
    __builtin_amdgcn_s_setprio(1);
#pragma unroll
    for (int i = 0; i < 4; ++i) {
      int row = (qtr * 4 + i) * 16 + lq;
      bf16x8 kf = *(const bf16x8*)((const char*)lds + row * 64 +
                                   ((lg ^ ((row >> 1) & 3)) << 4));
      sim[0][i] = MFMA32(kf, qf0, sim[0][i], 0, 0, 0);
      sim[1][i] = MFMA32(kf, qf1, sim[1][i], 0, 0, 0);
    }
#pragma unroll
    for (int c2 = 0; c2 < 2; ++c2) {
      int chunk = qtr * 2 + c2;
      bf16x8 b0 = *(const bf16x8*)(bb0 + chunk * 32);
      bf16x8 b1 = *(const bf16x8*)(bb1 + chunk * 32);
      bf16x8 v0 = *(const bf16x8*)&Vt[lq * 260 + chunk * 32 + lg * 8];
      bf16x8 v1 = *(const bf16x8*)&Vt[(16 + lq) * 260 + chunk * 32 + lg * 8];
      BV[0][0] = MFMA32(b0, v0, BV[0][0], 0, 0, 0);
      BV[0][1] = MFMA32(b0, v1, BV[0][1], 0, 0, 0);
      BV[1][0] = MFMA32(b1, v0, BV[1][0], 0, 0, 0);
      BV[1][1] = MFMA32(b1, v1, BV[1][1], 0, 0, 0);
    }
    __builtin_amdgcn_s_setprio(0);

    bf16x4 af[2][4];
#pragma unroll
    for (int ri = 0; ri < 2; ++ri)
#pragma unroll
      for (int i = 0; i < 4; ++i)
        af[ri][i] = pk4(__builtin_amdgcn_exp2f(sim[ri][i][0]),
                        __builtin_amdgcn_exp2f(sim[ri][i][1]),
                        __builtin_amdgcn_exp2f(sim[ri][i][2]),
                        __builtin_amdgcn_exp2f(sim[ri][i][3]));

    __builtin_amdgcn_s_setprio(1);
#pragma unroll
    for (int i = 0; i < 4; ++i) {
      int kc = qtr * 4 + i;
      bf16x4 vf0 = *(const bf16x4*)&Vt[lq * 260 + kc * 16 + lg * 4];
      bf16x4 vf1 = *(const bf16x4*)&Vt[(16 + lq) * 260 + kc * 16 + lg * 4];
#pragma unroll
      for (int ri = 0; ri < 2; ++ri) {
        U[ri][0] = MFMA16(af[ri][i], vf0, U[ri][0], 0, 0, 0);
        U[ri][1] = MFMA16(af[ri][i], vf1, U[ri][1], 0, 0, 0);
        L[ri]    = MFMA16(af[ri][i], ones, L[ri], 0, 0, 0);
      }
    }
    __builtin_amdgcn_s_setprio(0);
  }

  __syncthreads();  // done reading Ks/Qs; reuse Ks as Res [256][32]
  short* Res = lds;

#pragma unroll
  for (int ri = 0; ri < 2; ++ri) {
    f32x4 inv;
#pragma unroll
    for (int j = 0; j < 4; ++j) inv[j] = __builtin_amdgcn_rcpf(L[ri][j]);
#pragma unroll
    for (int ct = 0; ct < 2; ++ct) {
      int c = ct * 16 + lq;
      bf16x4 g4 = *(const bf16x4*)&Gs[c * 260 + rbase + ri * 16 + lg * 4];
#pragma unroll
      for (int j = 0; j < 4; ++j) {
        int rl = rbase + ri * 16 + lg * 4 + j;
        Res[rl * 32 + c] =
            bfbits((U[ri][ct][j] * inv[j] + BV[ri][ct][j]) *
                   bf2f((unsigned short)g4[j]));
      }
    }
  }
  __syncthreads();

  // head-major coalesced store: attn[h][s*256+row][32] — contiguous 16KB
  {
    int row = t >> 1, hf = t & 1;
    size_t o = (size_t)h * 1048576 + ((size_t)(s * 256 + row)) * 32 + hf * 16;
    bf16x8 r0 = *(const bf16x8*)&Res[row * 32 + hf * 16];
    bf16x8 r1 = *(const bf16x8*)&Res[row * 32 + hf * 16 + 8];
    *(bf16x8*)&attn_bf[o] = r0;
    *(bf16x8*)&attn_bf[o + 8] = r1;
  }
}

// ---------------------------------------------------------------------------
// gemm_out: attn[h][grow][32] (head-major) @ Woutt^T -> out f32.
// A-stage maps original k = h*32+c to head-major layout per 16B chunk.
// ---------------------------------------------------------------------------
__global__ __launch_bounds__(256) void gemm_out2(
    const short* __restrict__ A, const short* __restrict__ Wt,
    float* __restrict__ out) {
  __shared__ short As2[2][128 * 64];
  __shared__ short Bs2[2][128 * 64];
  int t = threadIdx.x;
  int lane = t & 63, wid = t >> 6;
  int lq = lane & 15, lg = lane >> 4;
  int wm = wid >> 1, wn = wid & 1;
  int r0 = blockIdx.x * 128, n0 = blockIdx.y * 128;

  auto stage = [&](int s, int buf) {
#pragma unroll
    for (int q = 0; q < 4; ++q) {
      int P = wid * 4096 + q * 1024 + lane * 16;
      int row = P >> 7, kb = P & 127;
      int klog = kb ^ ((row & 7) << 4);
      int kel = s * 64 + (klog >> 1);  // original k index (8-elem chunk)
      gll16(A + ((size_t)(kel >> 5) * 1048576 +
                 (size_t)(r0 + row) * 32 + (kel & 31)),
            (char*)&As2[buf][0] + wid * 4096 + q * 1024);
      gll16((const char*)Wt + ((size_t)(n0 + row) * 512 + s * 128 + klog),
            (char*)&Bs2[buf][0] + wid * 4096 + q * 1024);
    }
  };

  f32x4 acc[4][4];
#pragma unroll
  for (int a = 0; a < 4; ++a)
#pragma unroll
    for (int b = 0; b < 4; ++b) acc[a][b] = {0.f, 0.f, 0.f, 0.f};

  stage(0, 0);
  __syncthreads();
  for (int s = 0; s < 4; ++s) {
    if (s < 3) stage(s + 1, (s + 1) & 1);
    bf16x8 afr[4][2], bfr[4][2];
#pragma unroll
    for (int kcl = 0; kcl < 2; ++kcl) {
#pragma unroll
      for (int mf = 0; mf < 4; ++mf) {
        int row = wm * 64 + mf * 16 + lq;
        int kb = (((kcl << 6) | (lg << 4))) ^ ((row & 7) << 4);
        afr[mf][kcl] = *(const bf16x8*)((const char*)&As2[s & 1][0] + row * 128 + kb);
      }
#pragma unroll
      for (int nf = 0; nf < 4; ++nf) {
        int col = wn * 64 + nf * 16 + lq;
        int kb = (((kcl << 6) | (lg << 4))) ^ ((col & 7) << 4);
        bfr[nf][kcl] = *(const bf16x8*)((const char*)&Bs2[s & 1][0] + col * 128 + kb);
      }
    }
#pragma unroll
    for (int mf = 0; mf < 4; ++mf)
#pragma unroll
      for (int nf = 0; nf < 4; ++nf)
#pragma unroll
        for (int kcl = 0; kcl < 2; ++kcl)
          acc[mf][nf] = MFMA32(afr[mf][kcl], bfr[nf][kcl], acc[mf][nf], 0, 0, 0);
    __syncthreads();
  }
#pragma unroll
  for (int mf = 0; mf < 4; ++mf)
#pragma unroll
    for (int nf = 0; nf < 4; ++nf) {
      int col = n0 + wn * 64 + nf * 16 + lq;
#pragma unroll
      for (int j = 0; j < 4; ++j) {
        int row = r0 + wm * 64 + mf * 16 + lg * 4 + j;
        out[(size_t)row * 256 + col] = acc[mf][nf][j];
      }
    }
}

// ---------------------------------------------------------------------------
extern "C" void kernel_launch(void* const* d_in, const int* in_sizes, int n_in,
                              void* d_out, int out_size, void* d_ws,
                              size_t ws_size, hipStream_t stream) {
  const float* msa  = (const float*)d_in[0];
  const float* pair = (const float*)d_in[1];
  const float* Wg   = (const float*)d_in[2];
  const float* Wqkv = (const float*)d_in[3];
  const float* Wout = (const float*)d_in[4];
  const float* Bp   = (const float*)d_in[5];
  float* out = (float*)d_out;
  short* sw = (short*)d_ws;

  short* bias_bf = sw;                 //   524288 shorts
  short* attn_bf = sw + 524288;        //  8388608 (head-major [8][32768][32])
  short* Wh_bf   = sw + 8912896;       //   262144
  short* Woutt   = sw + 9175040;       //    65536
  short* X_bf    = sw + 9240576;       //  8388608

  hipLaunchKernelGGL(prep2_kernel, dim3(5888), dim3(256), 0, stream,
                     msa, pair, Bp, Wg, Wqkv, Wout,
                     X_bf, bias_bf, Wh_bf, Woutt);
  hipLaunchKernelGGL(fused_qkvattn, dim3(1024), dim3(512), 0, stream,
                     X_bf, Wh_bf, bias_bf, attn_bf);
  hipLaunchKernelGGL(gemm_out2, dim3(256, 2), dim3(256), 0, stream,
                     attn_bf, Woutt, out);
}